// Round 9
// baseline (2107.794 us; speedup 1.0000x reference)
//
#include <hip/hip_runtime.h>

#define BATCH 256
#define D 128
#define TT 64
#define NPG 60
#define NCC 30
#define NQQ 15
#define EPG 135
#define NPROP 5
#define SKI 10

typedef __attribute__((ext_vector_type(8))) short bf16x8;
typedef __attribute__((ext_vector_type(4))) float f32x4;

union U8 { bf16x8 v; uint4 u; };

__device__ __forceinline__ float bf2f(unsigned short u) {
    union { float f; unsigned int i; } t;
    t.i = ((unsigned int)u) << 16;
    return t.f;
}
__device__ __forceinline__ unsigned short f2bf(float f) {
    union { float f; unsigned int i; } t;
    t.f = f;
    unsigned int r = t.i + 0x7fffu + ((t.i >> 16) & 1u);
    return (unsigned short)(r >> 16);
}
__device__ __forceinline__ void split_bf(float v, unsigned short& hi, unsigned short& lo) {
    hi = f2bf(v);
    lo = f2bf(v - bf2f(hi));
}
// split 8 fp32 -> hi/lo bf16x8 fragments
__device__ __forceinline__ void split8(const float* z, bf16x8& ah, bf16x8& al) {
    U8 a, b;
    unsigned int ph[4], pl[4];
#pragma unroll
    for (int t = 0; t < 4; ++t) {
        unsigned short h0, l0, h1, l1;
        split_bf(z[2 * t], h0, l0);
        split_bf(z[2 * t + 1], h1, l1);
        ph[t] = (unsigned int)h0 | ((unsigned int)h1 << 16);
        pl[t] = (unsigned int)l0 | ((unsigned int)l1 << 16);
    }
    a.u = make_uint4(ph[0], ph[1], ph[2], ph[3]);
    b.u = make_uint4(pl[0], pl[1], pl[2], pl[3]);
    ah = a.v;
    al = b.v;
}

#define MFMA3(ah, al, bh, bl, acc)                                              \
    acc = __builtin_amdgcn_mfma_f32_16x16x32_bf16(ah, bh, acc, 0, 0, 0);        \
    acc = __builtin_amdgcn_mfma_f32_16x16x32_bf16(al, bh, acc, 0, 0, 0);        \
    acc = __builtin_amdgcn_mfma_f32_16x16x32_bf16(ah, bl, acc, 0, 0, 0);

// ---------------- edge-constant precompute: uv (512 fp32) ----------------
__global__ void k_prep_uv(const float* __restrict__ ew, const float* __restrict__ eb,
                          const float* __restrict__ w1, const float* __restrict__ b1,
                          float* __restrict__ uv) {
    int t = threadIdx.x;  // 0..255
    float u = 0.f, v = 0.f;
    for (int d = 0; d < D; ++d) {
        float wv = w1[(256 + d) * 256 + t];
        u += ew[d] * wv;
        v += eb[d] * wv;
    }
    uv[t] = u;
    uv[256 + t] = v + b1[t];
}

// ------------- weight prep: frag-major swizzled hi/lo bf16 planes -------------
// layout: elem o = ((nf*KS + ks)*64 + lane)*8 + t  maps to  [n][k] with
// n = nf*16 + (lane&15), k = ks*32 + (lane>>4)*8 + t.  One wave B-frag load = 1KB coalesced.
__global__ void k_prep_w2(const float* __restrict__ mw1, const float* __restrict__ mw2,
                          const float* __restrict__ uw1, const float* __restrict__ uw2,
                          const float* __restrict__ f1w, const float* __restrict__ f2w,
                          unsigned short* __restrict__ w1h, unsigned short* __restrict__ w1l,
                          unsigned short* __restrict__ w2h, unsigned short* __restrict__ w2l,
                          unsigned short* __restrict__ u1h, unsigned short* __restrict__ u1l,
                          unsigned short* __restrict__ u2h, unsigned short* __restrict__ u2l,
                          unsigned short* __restrict__ g1h, unsigned short* __restrict__ g1l,
                          unsigned short* __restrict__ g2h, unsigned short* __restrict__ g2l) {
    int idx = blockIdx.x * 512 + threadIdx.x;
    int o, KS;
    unsigned short *ph, *pl;
    int mtype;
    if (idx < 65536)        { o = idx;          KS = 4; ph = w1h; pl = w1l; mtype = 0; }
    else if (idx < 98304)   { o = idx - 65536;  KS = 8; ph = w2h; pl = w2l; mtype = 1; }
    else if (idx < 163840)  { o = idx - 98304;  KS = 8; ph = u1h; pl = u1l; mtype = 2; }
    else if (idx < 196608)  { o = idx - 163840; KS = 8; ph = u2h; pl = u2l; mtype = 3; }
    else if (idx < 204800)  { o = idx - 196608; KS = 4; ph = g1h; pl = g1l; mtype = 4; }
    else if (idx < 208896)  { o = idx - 204800; KS = 2; ph = g2h; pl = g2l; mtype = 5; }
    else return;
    int t = o & 7;
    int l = (o >> 3) & 63;
    int frag = o >> 9;
    int ks = frag % KS;
    int nfr = frag / KS;
    int n = nfr * 16 + (l & 15);
    int k = ks * 32 + (l >> 4) * 8 + t;
    float v;
    switch (mtype) {
        case 0: v = (n < 256) ? mw1[k * 256 + n] : mw1[(128 + k) * 256 + (n - 256)]; break;
        case 1: v = mw2[k * 128 + n]; break;
        case 2: v = uw1[k * 256 + n]; break;
        case 3: v = uw2[k * 128 + n]; break;
        case 4: v = f1w[k * 64 + n]; break;
        default: v = f2w[k * 64 + n]; break;
    }
    unsigned short hi, lo;
    split_bf(v, hi, lo);
    ph[o] = hi;
    pl[o] = lo;
}

// =================== megakernel: one block per graph ===================
__global__ __launch_bounds__(512) void k_mega(
    const float* __restrict__ nfeat, const float* __restrict__ efeat,
    const float* __restrict__ mfi,
    const float* __restrict__ enw, const float* __restrict__ enb,
    const float* __restrict__ uvg,
    const unsigned short* __restrict__ w1h, const unsigned short* __restrict__ w1l,
    const unsigned short* __restrict__ w2h, const unsigned short* __restrict__ w2l,
    const unsigned short* __restrict__ u1h, const unsigned short* __restrict__ u1l,
    const unsigned short* __restrict__ u2h, const unsigned short* __restrict__ u2l,
    const unsigned short* __restrict__ g1h, const unsigned short* __restrict__ g1l,
    const unsigned short* __restrict__ g2h, const unsigned short* __restrict__ g2l,
    const float* __restrict__ mb2, const float* __restrict__ ub1,
    const float* __restrict__ ub2, const float* __restrict__ f1b,
    const float* __restrict__ f2b,
    const int* __restrict__ fr, const int* __restrict__ to,
    float* __restrict__ out) {
    __shared__ float hS[60][132];        // residual h, fp32 (pad: stride%32==4 -> 2-way banks)
    __shared__ float H1S[45][516];       // H1 fp32; union: US[60][260], tail hid/t
    __shared__ float aggS[45][132];      // agg fp32; union: la[30][33], red[512]
    __shared__ float uS[256], vS[256];
    __shared__ int cfS[136], ctS[136];   // compact from-row / to-row (== agg row)
    __shared__ float efS[136], msS[136];
    __shared__ float b2S[128], ub1S[256], ub2S[128], f1bS[64], f2bS[64];

    int g = blockIdx.x;
    int tid = threadIdx.x;
    int wid = tid >> 6, lane = tid & 63;
    int l15 = lane & 15, l4 = lane >> 4;
    int rloc = l4 * 4;

    // ---- preload meta, biases, uv, encode h ----
    if (tid < 256) uS[tid] = uvg[tid];
    else vS[tid - 256] = uvg[tid];
    if (tid < 128) b2S[tid] = mb2[tid];
    if (tid < 256) ub1S[tid] = ub1[tid];
    if (tid < 128) ub2S[tid] = ub2[tid];
    if (tid < 64) { f1bS[tid] = f1b[tid]; f2bS[tid] = f2b[tid]; }
    if (tid < EPG) {
        int fn = fr[g * EPG + tid] - g * NPG;
        int tn = to[g * EPG + tid] - g * NPG;
        cfS[tid] = fn < 15 ? fn : fn - 15;
        ctS[tid] = tn < 15 ? tn : tn - 15;
        efS[tid] = efeat[g * EPG + tid];
        msS[tid] = mfi[g * EPG + tid];
    } else if (tid < 136) {
        cfS[tid] = 0; ctS[tid] = 0; efS[tid] = 0.f; msS[tid] = 0.f;
    }
    for (int i = tid; i < 60 * 128; i += 512) {
        int r = i >> 7, d = i & 127;
        hS[r][d] = nfeat[g * NPG + r] * enw[d] + enb[d];
    }
    __syncthreads();

    float* US = &H1S[0][0];   // [60][260] during upd phases

    for (int iter = 0; iter < NPROP; ++iter) {
        // ======== phase A: H1S[45][512] = gather(hS) @ W1^T ========
        // wave w: n-frags w*4 .. w*4+3
        {
            f32x4 acc[3][4] = {};
#pragma unroll
            for (int ks = 0; ks < 4; ++ks) {
                int k0 = ks * 32 + l4 * 8;
                bf16x8 ah[3], al[3];
#pragma unroll
                for (int i = 0; i < 3; ++i) {
                    int r = i * 16 + l15;
                    int hr = r < 15 ? r : (r < 45 ? r + 15 : 0);
                    float z[8];
                    *(float4*)&z[0] = *(const float4*)&hS[hr][k0];
                    *(float4*)&z[4] = *(const float4*)&hS[hr][k0 + 4];
                    split8(z, ah[i], al[i]);
                }
#pragma unroll
                for (int j = 0; j < 4; ++j) {
                    int nfr = wid * 4 + j;
                    int off = ((nfr * 4 + ks) * 64 + lane) * 8;
                    U8 th, tl;
                    th.u = *(const uint4*)(w1h + off);
                    tl.u = *(const uint4*)(w1l + off);
#pragma unroll
                    for (int i = 0; i < 3; ++i) { MFMA3(ah[i], al[i], th.v, tl.v, acc[i][j]); }
                }
            }
#pragma unroll
            for (int i = 0; i < 3; ++i)
#pragma unroll
                for (int j = 0; j < 4; ++j) {
                    int col = wid * 64 + j * 16 + l15;
#pragma unroll
                    for (int r = 0; r < 4; ++r) {
                        int m = i * 16 + rloc + r;
                        if (m < 45) H1S[m][col] = acc[i][j][r];
                    }
                }
        }
        // zero agg (read next phase)
        for (int i = tid; i < 45 * 132; i += 512) (&aggS[0][0])[i] = 0.f;
        __syncthreads();

        // ======== phase B: edge  Z(135x256)=relu(H1[f]+H1[t]+ef*u+v); agg += Z@W2 ========
        // wave w owns m-frag(s) w (+8 for w==0); loops all 8 n-frags. No k-loop barriers.
        for (int mf = wid; mf < 9; mf += 8) {
            f32x4 acc[8] = {};
#pragma unroll
            for (int ks = 0; ks < 8; ++ks) {
                int k0 = ks * 32 + l4 * 8;
                int e = mf * 16 + l15;
                int ee = e < EPG ? e : 0;
                int cf = cfS[ee], ct = ctS[ee];
                float ev = e < EPG ? efS[ee] : 0.f;
                float z[8], zb[8];
                *(float4*)&z[0] = *(const float4*)&H1S[cf][k0];
                *(float4*)&z[4] = *(const float4*)&H1S[cf][k0 + 4];
                *(float4*)&zb[0] = *(const float4*)&H1S[ct][256 + k0];
                *(float4*)&zb[4] = *(const float4*)&H1S[ct][256 + k0 + 4];
#pragma unroll
                for (int t = 0; t < 8; ++t)
                    z[t] = fmaxf(z[t] + zb[t] + ev * uS[k0 + t] + vS[k0 + t], 0.f);
                bf16x8 ah, al;
                split8(z, ah, al);
#pragma unroll
                for (int j = 0; j < 8; ++j) {
                    int off = ((j * 8 + ks) * 64 + lane) * 8;
                    U8 th, tl;
                    th.u = *(const uint4*)(w2h + off);
                    tl.u = *(const uint4*)(w2l + off);
                    MFMA3(ah, al, th.v, tl.v, acc[j]);
                }
            }
#pragma unroll
            for (int j = 0; j < 8; ++j) {
                int col = j * 16 + l15;
                float bias = b2S[col];
#pragma unroll
                for (int r = 0; r < 4; ++r) {
                    int e2 = mf * 16 + rloc + r;
                    if (e2 < EPG)
                        atomicAdd(&aggS[ctS[e2]][col], (acc[j][r] + bias) * msS[e2]);
                }
            }
        }
        __syncthreads();

        // ======== phase C: US[60][256] = relu([agg|h] @ Uw1^T + b1) ========
        // wave: m-frag = wid>>1, n-half = wid&1 (8 n-frags each)
        {
            int mf = wid >> 1, nh = wid & 1;
            int p = mf * 16 + l15;
            int ar = p < 15 ? p : (p < 60 ? p - 15 : 0);
            bool zr_agg = (p >= 15 && p < 30) || p >= 60;
            int hr = p < 60 ? p : 0;
            bool zr_h = p >= 60;
            f32x4 acc[8] = {};
#pragma unroll
            for (int ks = 0; ks < 8; ++ks) {
                int k0 = ks * 32 + l4 * 8;
                float z[8];
                if (ks < 4) {
                    *(float4*)&z[0] = *(const float4*)&aggS[ar][k0];
                    *(float4*)&z[4] = *(const float4*)&aggS[ar][k0 + 4];
#pragma unroll
                    for (int t = 0; t < 8; ++t) z[t] = zr_agg ? 0.f : z[t];
                } else {
                    *(float4*)&z[0] = *(const float4*)&hS[hr][k0 - 128];
                    *(float4*)&z[4] = *(const float4*)&hS[hr][k0 - 128 + 4];
#pragma unroll
                    for (int t = 0; t < 8; ++t) z[t] = zr_h ? 0.f : z[t];
                }
                bf16x8 ah, al;
                split8(z, ah, al);
#pragma unroll
                for (int j = 0; j < 8; ++j) {
                    int nfr = nh * 8 + j;
                    int off = ((nfr * 8 + ks) * 64 + lane) * 8;
                    U8 th, tl;
                    th.u = *(const uint4*)(u1h + off);
                    tl.u = *(const uint4*)(u1l + off);
                    MFMA3(ah, al, th.v, tl.v, acc[j]);
                }
            }
            __syncthreads();  // H1S (edge inputs) dead; safe to overwrite as US
#pragma unroll
            for (int j = 0; j < 8; ++j) {
                int col = nh * 128 + j * 16 + l15;
                float bias = ub1S[col];
#pragma unroll
                for (int r = 0; r < 4; ++r) {
                    int m = mf * 16 + rloc + r;
                    if (m < 60) US[m * 260 + col] = fmaxf(acc[j][r] + bias, 0.f);
                }
            }
        }
        __syncthreads();

        // ======== phase D: hS += US @ Uw2^T + b2 ========
        {
            int mf = wid >> 1, nh = wid & 1;
            int p = mf * 16 + l15;
            int pr = p < 60 ? p : 59;
            f32x4 acc[4] = {};
#pragma unroll
            for (int ks = 0; ks < 8; ++ks) {
                int k0 = ks * 32 + l4 * 8;
                float z[8];
                *(float4*)&z[0] = *(const float4*)&US[pr * 260 + k0];
                *(float4*)&z[4] = *(const float4*)&US[pr * 260 + k0 + 4];
                bf16x8 ah, al;
                split8(z, ah, al);
#pragma unroll
                for (int j = 0; j < 4; ++j) {
                    int nfr = nh * 4 + j;
                    int off = ((nfr * 8 + ks) * 64 + lane) * 8;
                    U8 th, tl;
                    th.u = *(const uint4*)(u2h + off);
                    tl.u = *(const uint4*)(u2l + off);
                    MFMA3(ah, al, th.v, tl.v, acc[j]);
                }
            }
#pragma unroll
            for (int j = 0; j < 4; ++j) {
                int col = nh * 64 + j * 16 + l15;
                float bias = ub2S[col];
#pragma unroll
                for (int r = 0; r < 4; ++r) {
                    int m = mf * 16 + rloc + r;
                    if (m < 60) hS[m][col] += acc[j][r] + bias;
                }
            }
        }
        __syncthreads();
    }

    // =================== tail: transform + Sinkhorn + score ===================
    float* hid = &H1S[0][0];        // [45][68]
    float* tS = hid + 45 * 68;      // [45][68]
    float* la = &aggS[0][0];        // [30][33]
    float* red = la + 1024;         // [512]

    // ft1: hid = relu(rows@f1w + b1); rows: compact r -> h row (q 0-14, c 30-59)
    if (wid < 6) {
        int mf = wid >> 1, nh = wid & 1;
        f32x4 acc[2] = {};
#pragma unroll
        for (int ks = 0; ks < 4; ++ks) {
            int k0 = ks * 32 + l4 * 8;
            int r = mf * 16 + l15;
            int hr = r < 15 ? r : (r < 45 ? r + 15 : 0);
            float z[8];
            *(float4*)&z[0] = *(const float4*)&hS[hr][k0];
            *(float4*)&z[4] = *(const float4*)&hS[hr][k0 + 4];
            bf16x8 ah, al;
            split8(z, ah, al);
#pragma unroll
            for (int j = 0; j < 2; ++j) {
                int nfr = nh * 2 + j;
                int off = ((nfr * 4 + ks) * 64 + lane) * 8;
                U8 th, tl;
                th.u = *(const uint4*)(g1h + off);
                tl.u = *(const uint4*)(g1l + off);
                MFMA3(ah, al, th.v, tl.v, acc[j]);
            }
        }
#pragma unroll
        for (int j = 0; j < 2; ++j) {
            int col = nh * 32 + j * 16 + l15;
            float bias = f1bS[col];
#pragma unroll
            for (int r = 0; r < 4; ++r) {
                int m = mf * 16 + rloc + r;
                if (m < 45) hid[m * 68 + col] = fmaxf(acc[j][r] + bias, 0.f);
            }
        }
    }
    __syncthreads();
    // ft2: tS = hid @ f2w + b2
    if (wid < 6) {
        int mf = wid >> 1, nh = wid & 1;
        f32x4 acc[2] = {};
#pragma unroll
        for (int ks = 0; ks < 2; ++ks) {
            int k0 = ks * 32 + l4 * 8;
            int r = mf * 16 + l15;
            int hr = r < 45 ? r : 0;
            float z[8];
            *(float4*)&z[0] = *(const float4*)&hid[hr * 68 + k0];
            *(float4*)&z[4] = *(const float4*)&hid[hr * 68 + k0 + 4];
            bf16x8 ah, al;
            split8(z, ah, al);
#pragma unroll
            for (int j = 0; j < 2; ++j) {
                int nfr = nh * 2 + j;
                int off = ((nfr * 2 + ks) * 64 + lane) * 8;
                U8 th, tl;
                th.u = *(const uint4*)(g2h + off);
                tl.u = *(const uint4*)(g2l + off);
                MFMA3(ah, al, th.v, tl.v, acc[j]);
            }
        }
#pragma unroll
        for (int j = 0; j < 2; ++j) {
            int col = nh * 32 + j * 16 + l15;
            float bias = f2bS[col];
#pragma unroll
            for (int r = 0; r < 4; ++r) {
                int m = mf * 16 + rloc + r;
                if (m < 45) tS[m * 68 + col] = acc[j][r] + bias;
            }
        }
    }
    __syncthreads();
    // la = 10 * tq @ tc^T ; q rows >= 15 are zero logits (participate in sinkhorn)
    for (int e = tid; e < NCC * NCC; e += 512) {
        int q = e / NCC, c = e % NCC;
        float s = 0.f;
        if (q < NQQ) {
#pragma unroll 4
            for (int k = 0; k < TT; k++) s += tS[q * 68 + k] * tS[(15 + c) * 68 + k];
            s *= 10.0f;
        }
        la[q * 33 + c] = s;
    }
    __syncthreads();
    int grp = tid >> 3, k8 = tid & 7;
    for (int it = 0; it < SKI; ++it) {
        if (grp < NCC) {  // row lse
            float v[4], m = -INFINITY;
#pragma unroll
            for (int t = 0; t < 4; t++) {
                int c = k8 * 4 + t;
                v[t] = (c < NCC) ? la[grp * 33 + c] : -INFINITY;
                m = fmaxf(m, v[t]);
            }
            m = fmaxf(m, __shfl_xor(m, 1));
            m = fmaxf(m, __shfl_xor(m, 2));
            m = fmaxf(m, __shfl_xor(m, 4));
            float s = 0.f;
#pragma unroll
            for (int t = 0; t < 4; t++)
                if (k8 * 4 + t < NCC) s += __expf(v[t] - m);
            s += __shfl_xor(s, 1);
            s += __shfl_xor(s, 2);
            s += __shfl_xor(s, 4);
            float lse = m + __logf(s);
#pragma unroll
            for (int t = 0; t < 4; t++) {
                int c = k8 * 4 + t;
                if (c < NCC) la[grp * 33 + c] = v[t] - lse;
            }
        }
        __syncthreads();
        if (grp < NCC) {  // col lse
            float v[4], m = -INFINITY;
#pragma unroll
            for (int t = 0; t < 4; t++) {
                int q = k8 * 4 + t;
                v[t] = (q < NCC) ? la[q * 33 + grp] : -INFINITY;
                m = fmaxf(m, v[t]);
            }
            m = fmaxf(m, __shfl_xor(m, 1));
            m = fmaxf(m, __shfl_xor(m, 2));
            m = fmaxf(m, __shfl_xor(m, 4));
            float s = 0.f;
#pragma unroll
            for (int t = 0; t < 4; t++)
                if (k8 * 4 + t < NCC) s += __expf(v[t] - m);
            s += __shfl_xor(s, 1);
            s += __shfl_xor(s, 2);
            s += __shfl_xor(s, 4);
            float lse = m + __logf(s);
#pragma unroll
            for (int t = 0; t < 4; t++) {
                int q = k8 * 4 + t;
                if (q < NCC) la[q * 33 + grp] = v[t] - lse;
            }
        }
        __syncthreads();
    }
    for (int e = tid; e < NCC * NCC; e += 512) {
        int q = e / NCC, c = e % NCC;
        la[q * 33 + c] = __expf(la[q * 33 + c]);
    }
    __syncthreads();
    // moved + score: q_emb rows = h rows 0..29; c_emb = h rows 30..59
    float part = 0.f;
    for (int idx = tid; idx < NCC * D; idx += 512) {
        int q = idx >> 7, d = idx & 127;
        float mv = 0.f;
#pragma unroll 5
        for (int c = 0; c < NCC; c++) mv += la[q * 33 + c] * hS[30 + c][d];
        part += fmaxf(hS[q][d] - mv, 0.f);
    }
    red[tid] = part;
    __syncthreads();
    for (int s2 = 256; s2 > 0; s2 >>= 1) {
        if (tid < s2) red[tid] += red[tid + s2];
        __syncthreads();
    }
    if (tid == 0) out[g] = -red[0];
}

extern "C" void kernel_launch(void* const* d_in, const int* in_sizes, int n_in,
                              void* d_out, int out_size, void* d_ws, size_t ws_size,
                              hipStream_t stream) {
    const float* nf  = (const float*)d_in[0];
    const float* ef  = (const float*)d_in[1];
    const float* mfi = (const float*)d_in[2];
    const float* enw = (const float*)d_in[3];
    const float* enb = (const float*)d_in[4];
    const float* eew = (const float*)d_in[5];
    const float* eeb = (const float*)d_in[6];
    const float* mw1 = (const float*)d_in[7];
    const float* mb1 = (const float*)d_in[8];
    const float* mw2 = (const float*)d_in[9];
    const float* mb2 = (const float*)d_in[10];
    const float* uw1 = (const float*)d_in[11];
    const float* ub1 = (const float*)d_in[12];
    const float* uw2 = (const float*)d_in[13];
    const float* ub2 = (const float*)d_in[14];
    const float* f1w = (const float*)d_in[15];
    const float* f1b = (const float*)d_in[16];
    const float* f2w = (const float*)d_in[17];
    const float* f2b = (const float*)d_in[18];
    const int* fr = (const int*)d_in[19];
    const int* to = (const int*)d_in[20];
    float* out = (float*)d_out;

    // workspace: uv + 12 frag-major weight planes
    char* base = (char*)d_ws;
    float* uv = (float*)base;
    unsigned short* w = (unsigned short*)(base + 4096);
    unsigned short* w1h = w;            unsigned short* w1l = w1h + 65536;
    unsigned short* w2h = w1l + 65536;  unsigned short* w2l = w2h + 32768;
    unsigned short* u1h = w2l + 32768;  unsigned short* u1l = u1h + 65536;
    unsigned short* u2h = u1l + 65536;  unsigned short* u2l = u2h + 32768;
    unsigned short* g1h = u2l + 32768;  unsigned short* g1l = g1h + 8192;
    unsigned short* g2h = g1l + 8192;   unsigned short* g2l = g2h + 4096;

    k_prep_uv<<<1, 256, 0, stream>>>(eew, eeb, mw1, mb1, uv);
    k_prep_w2<<<408, 512, 0, stream>>>(mw1, mw2, uw1, uw2, f1w, f2w,
                                       w1h, w1l, w2h, w2l, u1h, u1l, u2h, u2l,
                                       g1h, g1l, g2h, g2l);
    k_mega<<<BATCH, 512, 0, stream>>>(nf, ef, mfi, enw, enb, uv,
                                      w1h, w1l, w2h, w2l, u1h, u1l, u2h, u2l,
                                      g1h, g1l, g2h, g2l,
                                      mb2, ub1, ub2, f1b, f2b, fr, to, out);
}

// Round 10
// 371.215 us; speedup vs baseline: 5.6781x; 5.6781x over previous
//
#include <hip/hip_runtime.h>

#define BATCH 256
#define D 128
#define TT 64
#define NPG 60
#define NCC 30
#define NQQ 15
#define EPG 135
#define NPROP 5
#define SKI 10

typedef __attribute__((ext_vector_type(8))) short bf16x8;
typedef __attribute__((ext_vector_type(4))) float f32x4;

union U8 { bf16x8 v; uint4 u; };

__device__ __forceinline__ unsigned short f2bf(float f) {
    union { float f; unsigned int i; } t;
    t.f = f;
    unsigned int r = t.i + 0x7fffu + ((t.i >> 16) & 1u);
    return (unsigned short)(r >> 16);
}
__device__ __forceinline__ float bf2f(unsigned short u) {
    union { float f; unsigned int i; } t;
    t.i = ((unsigned int)u) << 16;
    return t.f;
}
__device__ __forceinline__ void split_bf(float v, unsigned short& hi, unsigned short& lo) {
    hi = f2bf(v);
    lo = f2bf(v - bf2f(hi));
}

// truncation split of 8 fp32 (all scalar, no address-taken arrays -> no scratch)
// hi = trunc16(x), lo = trunc16(x - hi); residual ~2^-16 relative
__device__ __forceinline__ void splitv(float4 a, float4 b, bf16x8& hi, bf16x8& lo) {
    unsigned int ia0=__float_as_uint(a.x), ia1=__float_as_uint(a.y);
    unsigned int ia2=__float_as_uint(a.z), ia3=__float_as_uint(a.w);
    unsigned int ib0=__float_as_uint(b.x), ib1=__float_as_uint(b.y);
    unsigned int ib2=__float_as_uint(b.z), ib3=__float_as_uint(b.w);
    U8 uh, ul;
    uh.u = make_uint4((ia0>>16)|(ia1&0xffff0000u), (ia2>>16)|(ia3&0xffff0000u),
                      (ib0>>16)|(ib1&0xffff0000u), (ib2>>16)|(ib3&0xffff0000u));
    float r0 = a.x - __uint_as_float(ia0&0xffff0000u);
    float r1 = a.y - __uint_as_float(ia1&0xffff0000u);
    float r2 = a.z - __uint_as_float(ia2&0xffff0000u);
    float r3 = a.w - __uint_as_float(ia3&0xffff0000u);
    float r4 = b.x - __uint_as_float(ib0&0xffff0000u);
    float r5 = b.y - __uint_as_float(ib1&0xffff0000u);
    float r6 = b.z - __uint_as_float(ib2&0xffff0000u);
    float r7 = b.w - __uint_as_float(ib3&0xffff0000u);
    ul.u = make_uint4((__float_as_uint(r0)>>16)|(__float_as_uint(r1)&0xffff0000u),
                      (__float_as_uint(r2)>>16)|(__float_as_uint(r3)&0xffff0000u),
                      (__float_as_uint(r4)>>16)|(__float_as_uint(r5)&0xffff0000u),
                      (__float_as_uint(r6)>>16)|(__float_as_uint(r7)&0xffff0000u));
    hi = uh.v; lo = ul.v;
}

#define MFMA3(ah, al, bh, bl, acc)                                              \
    acc = __builtin_amdgcn_mfma_f32_16x16x32_bf16(ah, bh, acc, 0, 0, 0);        \
    acc = __builtin_amdgcn_mfma_f32_16x16x32_bf16(al, bh, acc, 0, 0, 0);        \
    acc = __builtin_amdgcn_mfma_f32_16x16x32_bf16(ah, bl, acc, 0, 0, 0);

// ---------------- edge-constant precompute: uv (512 fp32) ----------------
__global__ void k_prep_uv(const float* __restrict__ ew, const float* __restrict__ eb,
                          const float* __restrict__ w1, const float* __restrict__ b1,
                          float* __restrict__ uv) {
    int t = threadIdx.x;  // 0..255
    float u = 0.f, v = 0.f;
    for (int d = 0; d < D; ++d) {
        float wv = w1[(256 + d) * 256 + t];
        u += ew[d] * wv;
        v += eb[d] * wv;
    }
    uv[t] = u;
    uv[256 + t] = v + b1[t];
}

// ------------- weight prep: frag-major hi/lo bf16 planes (RNE split) -------------
// elem o = ((nf*KS + ks)*64 + lane)*8 + t  ->  n = nf*16 + (lane&15), k = ks*32 + (lane>>4)*8 + t
__global__ void k_prep_w2(const float* __restrict__ mw1, const float* __restrict__ mw2,
                          const float* __restrict__ uw1, const float* __restrict__ uw2,
                          const float* __restrict__ f1w, const float* __restrict__ f2w,
                          unsigned short* __restrict__ w1h, unsigned short* __restrict__ w1l,
                          unsigned short* __restrict__ w2h, unsigned short* __restrict__ w2l,
                          unsigned short* __restrict__ u1h, unsigned short* __restrict__ u1l,
                          unsigned short* __restrict__ u2h, unsigned short* __restrict__ u2l,
                          unsigned short* __restrict__ g1h, unsigned short* __restrict__ g1l,
                          unsigned short* __restrict__ g2h, unsigned short* __restrict__ g2l) {
    int idx = blockIdx.x * 512 + threadIdx.x;
    int o, KS;
    unsigned short *ph, *pl;
    int mtype;
    if (idx < 65536)        { o = idx;          KS = 4; ph = w1h; pl = w1l; mtype = 0; }
    else if (idx < 98304)   { o = idx - 65536;  KS = 8; ph = w2h; pl = w2l; mtype = 1; }
    else if (idx < 163840)  { o = idx - 98304;  KS = 8; ph = u1h; pl = u1l; mtype = 2; }
    else if (idx < 196608)  { o = idx - 163840; KS = 8; ph = u2h; pl = u2l; mtype = 3; }
    else if (idx < 204800)  { o = idx - 196608; KS = 4; ph = g1h; pl = g1l; mtype = 4; }
    else if (idx < 208896)  { o = idx - 204800; KS = 2; ph = g2h; pl = g2l; mtype = 5; }
    else return;
    int t = o & 7;
    int l = (o >> 3) & 63;
    int frag = o >> 9;
    int ks = frag % KS;
    int nfr = frag / KS;
    int n = nfr * 16 + (l & 15);
    int k = ks * 32 + (l >> 4) * 8 + t;
    float v;
    switch (mtype) {
        case 0: v = (n < 256) ? mw1[k * 256 + n] : mw1[(128 + k) * 256 + (n - 256)]; break;
        case 1: v = mw2[k * 128 + n]; break;
        case 2: v = uw1[k * 256 + n]; break;
        case 3: v = uw2[k * 128 + n]; break;
        case 4: v = f1w[k * 64 + n]; break;
        default: v = f2w[k * 64 + n]; break;
    }
    unsigned short hi, lo;
    split_bf(v, hi, lo);
    ph[o] = hi;
    pl[o] = lo;
}

// =================== megakernel: one block per graph ===================
__global__ __launch_bounds__(512, 2) void k_mega(
    const float* __restrict__ nfeat, const float* __restrict__ efeat,
    const float* __restrict__ mfi,
    const float* __restrict__ enw, const float* __restrict__ enb,
    const float* __restrict__ uvg,
    const unsigned short* __restrict__ w1h, const unsigned short* __restrict__ w1l,
    const unsigned short* __restrict__ w2h, const unsigned short* __restrict__ w2l,
    const unsigned short* __restrict__ u1h, const unsigned short* __restrict__ u1l,
    const unsigned short* __restrict__ u2h, const unsigned short* __restrict__ u2l,
    const unsigned short* __restrict__ g1h, const unsigned short* __restrict__ g1l,
    const unsigned short* __restrict__ g2h, const unsigned short* __restrict__ g2l,
    const float* __restrict__ mb2, const float* __restrict__ ub1,
    const float* __restrict__ ub2, const float* __restrict__ f1b,
    const float* __restrict__ f2b,
    const int* __restrict__ fr, const int* __restrict__ to,
    float* __restrict__ out) {
    __shared__ __align__(16) float hS[60][132];    // residual h fp32
    __shared__ __align__(16) float H1S[45][516];   // H1 fp32; overlay: US[60][260]; tail hid/t
    __shared__ __align__(16) float aggS[45][132];  // agg fp32; overlay: B-phase Z-frag stage; tail la/red
    __shared__ float uS[256], vS[256];
    __shared__ int cfS[144], ctS[144];
    __shared__ float efS[144], msS[144];
    __shared__ float b2S[128], ub1S[256], ub2S[128], f1bS[64], f2bS[64];

    int g = blockIdx.x;
    int tid = threadIdx.x;
    int wid = tid >> 6, lane = tid & 63;
    int l15 = lane & 15, l4 = lane >> 4;
    int rloc = l4 * 4;

    // ---- preload ----
    if (tid < 256) uS[tid] = uvg[tid];
    else vS[tid - 256] = uvg[tid];
    if (tid < 128) b2S[tid] = mb2[tid];
    if (tid < 256) ub1S[tid] = ub1[tid];
    if (tid < 128) ub2S[tid] = ub2[tid];
    if (tid < 64) { f1bS[tid] = f1b[tid]; f2bS[tid] = f2b[tid]; }
    if (tid < EPG) {
        int fn = fr[g * EPG + tid] - g * NPG;
        int tn = to[g * EPG + tid] - g * NPG;
        cfS[tid] = fn < 15 ? fn : fn - 15;
        ctS[tid] = tn < 15 ? tn : tn - 15;
        efS[tid] = efeat[g * EPG + tid];
        msS[tid] = mfi[g * EPG + tid];
    } else if (tid < 144) {
        cfS[tid] = 0; ctS[tid] = 0; efS[tid] = 0.f; msS[tid] = 0.f;
    }
    for (int i = tid; i < 60 * 128; i += 512) {
        int r = i >> 7, d = i & 127;
        hS[r][d] = nfeat[g * NPG + r] * enw[d] + enb[d];
    }
    __syncthreads();

    float* US = &H1S[0][0];                 // [60][260] during C/D
    char* zb = (char*)&aggS[0][0];          // B-phase Z-frag staging (18,432B <= 23,760B)

    for (int iter = 0; iter < NPROP; ++iter) {
        // ======== A: H1S = gather(hS) @ W1^T ; wave w -> n-frags w*4..w*4+3 ========
        {
            f32x4 acc[3][4] = {};
#pragma unroll
            for (int ks = 0; ks < 4; ++ks) {
                int k0 = ks * 32 + l4 * 8;
                bf16x8 ah[3], al[3];
#pragma unroll
                for (int i = 0; i < 3; ++i) {
                    int r = i * 16 + l15;
                    int hr = r < 15 ? r : (r < 45 ? r + 15 : 0);
                    float4 a0 = *(const float4*)&hS[hr][k0];
                    float4 a1 = *(const float4*)&hS[hr][k0 + 4];
                    splitv(a0, a1, ah[i], al[i]);
                }
#pragma unroll
                for (int j = 0; j < 4; ++j) {
                    int nfr = wid * 4 + j;
                    int off = ((nfr * 4 + ks) * 64 + lane) * 8;
                    U8 th, tl;
                    th.u = *(const uint4*)(w1h + off);
                    tl.u = *(const uint4*)(w1l + off);
#pragma unroll
                    for (int i = 0; i < 3; ++i) { MFMA3(ah[i], al[i], th.v, tl.v, acc[i][j]); }
                }
            }
#pragma unroll
            for (int i = 0; i < 3; ++i)
#pragma unroll
                for (int j = 0; j < 4; ++j) {
                    int col = wid * 64 + j * 16 + l15;
#pragma unroll
                    for (int r = 0; r < 4; ++r) {
                        int m = i * 16 + rloc + r;
                        if (m < 45) H1S[m][col] = acc[i][j][r];
                    }
                }
        }
        __syncthreads();

        // ======== B: Z(144x256)=relu(H1[f]+H1[t]+ef*u+v); agg += Z@W2 ========
        // per ks: cooperative Z-frag stage into aggS scratch; wave w = n-frag w
        {
            f32x4 accB[9] = {};
#pragma unroll
            for (int ks = 0; ks < 8; ++ks) {
                __syncthreads();   // prior reads of stage done
                for (int u = tid; u < 576; u += 512) {
                    int f = u >> 6, l = u & 63;
                    int e = f * 16 + (l & 15);
                    int k0 = ks * 32 + (l >> 4) * 8;
                    int ee = e < EPG ? e : 0;
                    int cf = cfS[ee], ct = ctS[ee];
                    float ev = e < EPG ? efS[ee] : 0.f;
                    float4 x0 = *(const float4*)&H1S[cf][k0];
                    float4 x1 = *(const float4*)&H1S[cf][k0 + 4];
                    float4 y0 = *(const float4*)&H1S[ct][256 + k0];
                    float4 y1 = *(const float4*)&H1S[ct][256 + k0 + 4];
                    x0.x = fmaxf(x0.x + y0.x + ev * uS[k0 + 0] + vS[k0 + 0], 0.f);
                    x0.y = fmaxf(x0.y + y0.y + ev * uS[k0 + 1] + vS[k0 + 1], 0.f);
                    x0.z = fmaxf(x0.z + y0.z + ev * uS[k0 + 2] + vS[k0 + 2], 0.f);
                    x0.w = fmaxf(x0.w + y0.w + ev * uS[k0 + 3] + vS[k0 + 3], 0.f);
                    x1.x = fmaxf(x1.x + y1.x + ev * uS[k0 + 4] + vS[k0 + 4], 0.f);
                    x1.y = fmaxf(x1.y + y1.y + ev * uS[k0 + 5] + vS[k0 + 5], 0.f);
                    x1.z = fmaxf(x1.z + y1.z + ev * uS[k0 + 6] + vS[k0 + 6], 0.f);
                    x1.w = fmaxf(x1.w + y1.w + ev * uS[k0 + 7] + vS[k0 + 7], 0.f);
                    bf16x8 zh, zl;
                    splitv(x0, x1, zh, zl);
                    U8 sh, sl; sh.v = zh; sl.v = zl;
                    *(uint4*)(zb + f * 2048 + l * 16) = sh.u;
                    *(uint4*)(zb + f * 2048 + 1024 + l * 16) = sl.u;
                }
                __syncthreads();
                int off = ((wid * 8 + ks) * 64 + lane) * 8;
                U8 th, tl;
                th.u = *(const uint4*)(w2h + off);
                tl.u = *(const uint4*)(w2l + off);
#pragma unroll
                for (int f = 0; f < 9; ++f) {
                    bf16x8 zh = *(bf16x8*)(zb + f * 2048 + lane * 16);
                    bf16x8 zl = *(bf16x8*)(zb + f * 2048 + 1024 + lane * 16);
                    MFMA3(zh, zl, th.v, tl.v, accB[f]);
                }
            }
            __syncthreads();
            for (int i = tid; i < 45 * 132; i += 512) (&aggS[0][0])[i] = 0.f;
            __syncthreads();
            {
                int col = wid * 16 + l15;
                float bias = b2S[col];
#pragma unroll
                for (int f = 0; f < 9; ++f)
#pragma unroll
                    for (int r = 0; r < 4; ++r) {
                        int e = f * 16 + rloc + r;
                        if (e < EPG)
                            atomicAdd(&aggS[ctS[e]][col], (accB[f][r] + bias) * msS[e]);
                    }
            }
        }
        __syncthreads();

        // ======== C: US[60][256] = relu([agg|h] @ Uw1^T + b1) ; wave w -> nf {2w,2w+1} ========
        {
            f32x4 accC[4][2] = {};
#pragma unroll
            for (int ks = 0; ks < 8; ++ks) {
                int k0 = ks * 32 + l4 * 8;
                bf16x8 bh[2], bl[2];
#pragma unroll
                for (int j = 0; j < 2; ++j) {
                    int nfr = wid * 2 + j;
                    int off = ((nfr * 8 + ks) * 64 + lane) * 8;
                    U8 th, tl;
                    th.u = *(const uint4*)(u1h + off);
                    tl.u = *(const uint4*)(u1l + off);
                    bh[j] = th.v; bl[j] = tl.v;
                }
#pragma unroll
                for (int mf = 0; mf < 4; ++mf) {
                    int p = mf * 16 + l15;
                    float4 z0, z1;
                    if (ks < 4) {
                        int ar = p < 15 ? p : (p < 60 ? p - 15 : 0);
                        z0 = *(const float4*)&aggS[ar][k0];
                        z1 = *(const float4*)&aggS[ar][k0 + 4];
                        float msk = (p >= 15 && p < 30) ? 0.f : 1.f;
                        z0.x *= msk; z0.y *= msk; z0.z *= msk; z0.w *= msk;
                        z1.x *= msk; z1.y *= msk; z1.z *= msk; z1.w *= msk;
                    } else {
                        int hr = p < 60 ? p : 0;
                        z0 = *(const float4*)&hS[hr][k0 - 128];
                        z1 = *(const float4*)&hS[hr][k0 - 128 + 4];
                    }
                    bf16x8 ah, al;
                    splitv(z0, z1, ah, al);
#pragma unroll
                    for (int j = 0; j < 2; ++j) { MFMA3(ah, al, bh[j], bl[j], accC[mf][j]); }
                }
            }
            __syncthreads();  // all waves done with H1S? (H1 last read in B) -> safe US writes
#pragma unroll
            for (int mf = 0; mf < 4; ++mf)
#pragma unroll
                for (int j = 0; j < 2; ++j) {
                    int col = (wid * 2 + j) * 16 + l15;
                    float bias = ub1S[col];
#pragma unroll
                    for (int r = 0; r < 4; ++r) {
                        int m = mf * 16 + rloc + r;
                        if (m < 60) US[m * 260 + col] = fmaxf(accC[mf][j][r] + bias, 0.f);
                    }
                }
        }
        __syncthreads();

        // ======== D: hS += US @ Uw2^T + b2 ; wave w -> nf w ========
        {
            f32x4 accD[4] = {};
#pragma unroll
            for (int ks = 0; ks < 8; ++ks) {
                int k0 = ks * 32 + l4 * 8;
                int off = ((wid * 8 + ks) * 64 + lane) * 8;
                U8 th, tl;
                th.u = *(const uint4*)(u2h + off);
                tl.u = *(const uint4*)(u2l + off);
#pragma unroll
                for (int mf = 0; mf < 4; ++mf) {
                    int p = mf * 16 + l15;
                    int pr = p < 60 ? p : 0;
                    float4 z0 = *(const float4*)&US[pr * 260 + k0];
                    float4 z1 = *(const float4*)&US[pr * 260 + k0 + 4];
                    bf16x8 ah, al;
                    splitv(z0, z1, ah, al);
                    MFMA3(ah, al, th.v, tl.v, accD[mf]);
                }
            }
#pragma unroll
            for (int mf = 0; mf < 4; ++mf) {
                int col = wid * 16 + l15;
                float bias = ub2S[col];
#pragma unroll
                for (int r = 0; r < 4; ++r) {
                    int m = mf * 16 + rloc + r;
                    if (m < 60) hS[m][col] += accD[mf][r] + bias;
                }
            }
        }
        __syncthreads();
    }

    // =================== tail: transform + Sinkhorn + score ===================
    float* hid = &H1S[0][0];        // [45][68]
    float* tS = hid + 45 * 68;      // [45][68]
    float* la = &aggS[0][0];        // [30][33]
    float* red = la + 1024;         // [512]

    if (wid < 6) {  // ft1: hid = relu(rows @ f1w + b1)
        int mf = wid >> 1, nh = wid & 1;
        f32x4 acc[2] = {};
#pragma unroll
        for (int ks = 0; ks < 4; ++ks) {
            int k0 = ks * 32 + l4 * 8;
            int r = mf * 16 + l15;
            int hr = r < 15 ? r : (r < 45 ? r + 15 : 0);
            float4 a0 = *(const float4*)&hS[hr][k0];
            float4 a1 = *(const float4*)&hS[hr][k0 + 4];
            bf16x8 ah, al;
            splitv(a0, a1, ah, al);
#pragma unroll
            for (int j = 0; j < 2; ++j) {
                int nfr = nh * 2 + j;
                int off = ((nfr * 4 + ks) * 64 + lane) * 8;
                U8 th, tl;
                th.u = *(const uint4*)(g1h + off);
                tl.u = *(const uint4*)(g1l + off);
                MFMA3(ah, al, th.v, tl.v, acc[j]);
            }
        }
#pragma unroll
        for (int j = 0; j < 2; ++j) {
            int col = nh * 32 + j * 16 + l15;
            float bias = f1bS[col];
#pragma unroll
            for (int r = 0; r < 4; ++r) {
                int m = mf * 16 + rloc + r;
                if (m < 45) hid[m * 68 + col] = fmaxf(acc[j][r] + bias, 0.f);
            }
        }
    }
    __syncthreads();
    if (wid < 6) {  // ft2: tS = hid @ f2w + b2
        int mf = wid >> 1, nh = wid & 1;
        f32x4 acc[2] = {};
#pragma unroll
        for (int ks = 0; ks < 2; ++ks) {
            int k0 = ks * 32 + l4 * 8;
            int r = mf * 16 + l15;
            int hr = r < 45 ? r : 0;
            float4 a0 = *(const float4*)&hid[hr * 68 + k0];
            float4 a1 = *(const float4*)&hid[hr * 68 + k0 + 4];
            bf16x8 ah, al;
            splitv(a0, a1, ah, al);
#pragma unroll
            for (int j = 0; j < 2; ++j) {
                int nfr = nh * 2 + j;
                int off = ((nfr * 2 + ks) * 64 + lane) * 8;
                U8 th, tl;
                th.u = *(const uint4*)(g2h + off);
                tl.u = *(const uint4*)(g2l + off);
                MFMA3(ah, al, th.v, tl.v, acc[j]);
            }
        }
#pragma unroll
        for (int j = 0; j < 2; ++j) {
            int col = nh * 32 + j * 16 + l15;
            float bias = f2bS[col];
#pragma unroll
            for (int r = 0; r < 4; ++r) {
                int m = mf * 16 + rloc + r;
                if (m < 45) tS[m * 68 + col] = acc[j][r] + bias;
            }
        }
    }
    __syncthreads();
    for (int e = tid; e < NCC * NCC; e += 512) {
        int q = e / NCC, c = e % NCC;
        float s = 0.f;
        if (q < NQQ) {
#pragma unroll 4
            for (int k = 0; k < TT; k++) s += tS[q * 68 + k] * tS[(15 + c) * 68 + k];
            s *= 10.0f;
        }
        la[q * 33 + c] = s;
    }
    __syncthreads();
    int grp = tid >> 3, k8 = tid & 7;
    for (int it = 0; it < SKI; ++it) {
        if (grp < NCC) {
            float v0, v1, v2, v3, m;
            int c0 = k8 * 4;
            v0 = (c0 + 0 < NCC) ? la[grp * 33 + c0 + 0] : -INFINITY;
            v1 = (c0 + 1 < NCC) ? la[grp * 33 + c0 + 1] : -INFINITY;
            v2 = (c0 + 2 < NCC) ? la[grp * 33 + c0 + 2] : -INFINITY;
            v3 = (c0 + 3 < NCC) ? la[grp * 33 + c0 + 3] : -INFINITY;
            m = fmaxf(fmaxf(v0, v1), fmaxf(v2, v3));
            m = fmaxf(m, __shfl_xor(m, 1));
            m = fmaxf(m, __shfl_xor(m, 2));
            m = fmaxf(m, __shfl_xor(m, 4));
            float s = 0.f;
            if (c0 + 0 < NCC) s += __expf(v0 - m);
            if (c0 + 1 < NCC) s += __expf(v1 - m);
            if (c0 + 2 < NCC) s += __expf(v2 - m);
            if (c0 + 3 < NCC) s += __expf(v3 - m);
            s += __shfl_xor(s, 1);
            s += __shfl_xor(s, 2);
            s += __shfl_xor(s, 4);
            float lse = m + __logf(s);
            if (c0 + 0 < NCC) la[grp * 33 + c0 + 0] = v0 - lse;
            if (c0 + 1 < NCC) la[grp * 33 + c0 + 1] = v1 - lse;
            if (c0 + 2 < NCC) la[grp * 33 + c0 + 2] = v2 - lse;
            if (c0 + 3 < NCC) la[grp * 33 + c0 + 3] = v3 - lse;
        }
        __syncthreads();
        if (grp < NCC) {
            float v0, v1, v2, v3, m;
            int q0 = k8 * 4;
            v0 = (q0 + 0 < NCC) ? la[(q0 + 0) * 33 + grp] : -INFINITY;
            v1 = (q0 + 1 < NCC) ? la[(q0 + 1) * 33 + grp] : -INFINITY;
            v2 = (q0 + 2 < NCC) ? la[(q0 + 2) * 33 + grp] : -INFINITY;
            v3 = (q0 + 3 < NCC) ? la[(q0 + 3) * 33 + grp] : -INFINITY;
            m = fmaxf(fmaxf(v0, v1), fmaxf(v2, v3));
            m = fmaxf(m, __shfl_xor(m, 1));
            m = fmaxf(m, __shfl_xor(m, 2));
            m = fmaxf(m, __shfl_xor(m, 4));
            float s = 0.f;
            if (q0 + 0 < NCC) s += __expf(v0 - m);
            if (q0 + 1 < NCC) s += __expf(v1 - m);
            if (q0 + 2 < NCC) s += __expf(v2 - m);
            if (q0 + 3 < NCC) s += __expf(v3 - m);
            s += __shfl_xor(s, 1);
            s += __shfl_xor(s, 2);
            s += __shfl_xor(s, 4);
            float lse = m + __logf(s);
            if (q0 + 0 < NCC) la[(q0 + 0) * 33 + grp] = v0 - lse;
            if (q0 + 1 < NCC) la[(q0 + 1) * 33 + grp] = v1 - lse;
            if (q0 + 2 < NCC) la[(q0 + 2) * 33 + grp] = v2 - lse;
            if (q0 + 3 < NCC) la[(q0 + 3) * 33 + grp] = v3 - lse;
        }
        __syncthreads();
    }
    for (int e = tid; e < NCC * NCC; e += 512) {
        int q = e / NCC, c = e % NCC;
        la[q * 33 + c] = __expf(la[q * 33 + c]);
    }
    __syncthreads();
    float part = 0.f;
    for (int idx = tid; idx < NCC * D; idx += 512) {
        int q = idx >> 7, d = idx & 127;
        float mv = 0.f;
#pragma unroll 5
        for (int c = 0; c < NCC; c++) mv += la[q * 33 + c] * hS[30 + c][d];
        part += fmaxf(hS[q][d] - mv, 0.f);
    }
    red[tid] = part;
    __syncthreads();
    for (int s2 = 256; s2 > 0; s2 >>= 1) {
        if (tid < s2) red[tid] += red[tid + s2];
        __syncthreads();
    }
    if (tid == 0) out[g] = -red[0];
}

extern "C" void kernel_launch(void* const* d_in, const int* in_sizes, int n_in,
                              void* d_out, int out_size, void* d_ws, size_t ws_size,
                              hipStream_t stream) {
    const float* nf  = (const float*)d_in[0];
    const float* ef  = (const float*)d_in[1];
    const float* mfi = (const float*)d_in[2];
    const float* enw = (const float*)d_in[3];
    const float* enb = (const float*)d_in[4];
    const float* eew = (const float*)d_in[5];
    const float* eeb = (const float*)d_in[6];
    const float* mw1 = (const float*)d_in[7];
    const float* mb1 = (const float*)d_in[8];
    const float* mw2 = (const float*)d_in[9];
    const float* mb2 = (const float*)d_in[10];
    const float* uw1 = (const float*)d_in[11];
    const float* ub1 = (const float*)d_in[12];
    const float* uw2 = (const float*)d_in[13];
    const float* ub2 = (const float*)d_in[14];
    const float* f1w = (const float*)d_in[15];
    const float* f1b = (const float*)d_in[16];
    const float* f2w = (const float*)d_in[17];
    const float* f2b = (const float*)d_in[18];
    const int* fr = (const int*)d_in[19];
    const int* to = (const int*)d_in[20];
    float* out = (float*)d_out;

    char* base = (char*)d_ws;
    float* uv = (float*)base;
    unsigned short* w = (unsigned short*)(base + 4096);
    unsigned short* w1h = w;            unsigned short* w1l = w1h + 65536;
    unsigned short* w2h = w1l + 65536;  unsigned short* w2l = w2h + 32768;
    unsigned short* u1h = w2l + 32768;  unsigned short* u1l = u1h + 65536;
    unsigned short* u2h = u1l + 65536;  unsigned short* u2l = u2h + 32768;
    unsigned short* g1h = u2l + 32768;  unsigned short* g1l = g1h + 8192;
    unsigned short* g2h = g1l + 8192;   unsigned short* g2l = g2h + 4096;

    k_prep_uv<<<1, 256, 0, stream>>>(eew, eeb, mw1, mb1, uv);
    k_prep_w2<<<408, 512, 0, stream>>>(mw1, mw2, uw1, uw2, f1w, f2w,
                                       w1h, w1l, w2h, w2l, u1h, u1l, u2h, u2l,
                                       g1h, g1l, g2h, g2l);
    k_mega<<<BATCH, 512, 0, stream>>>(nf, ef, mfi, enw, enb, uv,
                                      w1h, w1l, w2h, w2l, u1h, u1l, u2h, u2l,
                                      g1h, g1l, g2h, g2l,
                                      mb2, ub1, ub2, f1b, f2b, fr, to, out);
}

// Round 11
// 370.644 us; speedup vs baseline: 5.6868x; 1.0015x over previous
//
#include <hip/hip_runtime.h>

#define BATCH 256
#define D 128
#define TT 64
#define NPG 60
#define NCC 30
#define NQQ 15
#define EPG 135
#define NPROP 5
#define SKI 10

typedef __attribute__((ext_vector_type(8))) short bf16x8;
typedef __attribute__((ext_vector_type(4))) float f32x4;

union U8 { bf16x8 v; uint4 u; };

__device__ __forceinline__ unsigned short f2bf(float f) {
    union { float f; unsigned int i; } t;
    t.f = f;
    unsigned int r = t.i + 0x7fffu + ((t.i >> 16) & 1u);
    return (unsigned short)(r >> 16);
}
__device__ __forceinline__ float bf2f(unsigned short u) {
    union { float f; unsigned int i; } t;
    t.i = ((unsigned int)u) << 16;
    return t.f;
}
__device__ __forceinline__ void split_bf(float v, unsigned short& hi, unsigned short& lo) {
    hi = f2bf(v);
    lo = f2bf(v - bf2f(hi));
}

// truncation split of 8 fp32 (all scalar -> registers, no scratch)
__device__ __forceinline__ void splitv(float4 a, float4 b, bf16x8& hi, bf16x8& lo) {
    unsigned int ia0=__float_as_uint(a.x), ia1=__float_as_uint(a.y);
    unsigned int ia2=__float_as_uint(a.z), ia3=__float_as_uint(a.w);
    unsigned int ib0=__float_as_uint(b.x), ib1=__float_as_uint(b.y);
    unsigned int ib2=__float_as_uint(b.z), ib3=__float_as_uint(b.w);
    U8 uh, ul;
    uh.u = make_uint4((ia0>>16)|(ia1&0xffff0000u), (ia2>>16)|(ia3&0xffff0000u),
                      (ib0>>16)|(ib1&0xffff0000u), (ib2>>16)|(ib3&0xffff0000u));
    float r0 = a.x - __uint_as_float(ia0&0xffff0000u);
    float r1 = a.y - __uint_as_float(ia1&0xffff0000u);
    float r2 = a.z - __uint_as_float(ia2&0xffff0000u);
    float r3 = a.w - __uint_as_float(ia3&0xffff0000u);
    float r4 = b.x - __uint_as_float(ib0&0xffff0000u);
    float r5 = b.y - __uint_as_float(ib1&0xffff0000u);
    float r6 = b.z - __uint_as_float(ib2&0xffff0000u);
    float r7 = b.w - __uint_as_float(ib3&0xffff0000u);
    ul.u = make_uint4((__float_as_uint(r0)>>16)|(__float_as_uint(r1)&0xffff0000u),
                      (__float_as_uint(r2)>>16)|(__float_as_uint(r3)&0xffff0000u),
                      (__float_as_uint(r4)>>16)|(__float_as_uint(r5)&0xffff0000u),
                      (__float_as_uint(r6)>>16)|(__float_as_uint(r7)&0xffff0000u));
    hi = uh.v; lo = ul.v;
}

#define MFMA3(ah, al, bh, bl, acc)                                              \
    acc = __builtin_amdgcn_mfma_f32_16x16x32_bf16(ah, bh, acc, 0, 0, 0);        \
    acc = __builtin_amdgcn_mfma_f32_16x16x32_bf16(al, bh, acc, 0, 0, 0);        \
    acc = __builtin_amdgcn_mfma_f32_16x16x32_bf16(ah, bl, acc, 0, 0, 0);

// ---------------- edge-constant precompute: uv (512 fp32) ----------------
__global__ void k_prep_uv(const float* __restrict__ ew, const float* __restrict__ eb,
                          const float* __restrict__ w1, const float* __restrict__ b1,
                          float* __restrict__ uv) {
    int t = threadIdx.x;  // 0..255
    float u = 0.f, v = 0.f;
    for (int d = 0; d < D; ++d) {
        float wv = w1[(256 + d) * 256 + t];
        u += ew[d] * wv;
        v += eb[d] * wv;
    }
    uv[t] = u;
    uv[256 + t] = v + b1[t];
}

// ------------- weight prep: frag-major hi/lo bf16 planes (RNE split) -------------
__global__ void k_prep_w2(const float* __restrict__ mw1, const float* __restrict__ mw2,
                          const float* __restrict__ uw1, const float* __restrict__ uw2,
                          const float* __restrict__ f1w, const float* __restrict__ f2w,
                          unsigned short* __restrict__ w1h, unsigned short* __restrict__ w1l,
                          unsigned short* __restrict__ w2h, unsigned short* __restrict__ w2l,
                          unsigned short* __restrict__ u1h, unsigned short* __restrict__ u1l,
                          unsigned short* __restrict__ u2h, unsigned short* __restrict__ u2l,
                          unsigned short* __restrict__ g1h, unsigned short* __restrict__ g1l,
                          unsigned short* __restrict__ g2h, unsigned short* __restrict__ g2l) {
    int idx = blockIdx.x * 512 + threadIdx.x;
    int o, KS;
    unsigned short *ph, *pl;
    int mtype;
    if (idx < 65536)        { o = idx;          KS = 4; ph = w1h; pl = w1l; mtype = 0; }
    else if (idx < 98304)   { o = idx - 65536;  KS = 8; ph = w2h; pl = w2l; mtype = 1; }
    else if (idx < 163840)  { o = idx - 98304;  KS = 8; ph = u1h; pl = u1l; mtype = 2; }
    else if (idx < 196608)  { o = idx - 163840; KS = 8; ph = u2h; pl = u2l; mtype = 3; }
    else if (idx < 204800)  { o = idx - 196608; KS = 4; ph = g1h; pl = g1l; mtype = 4; }
    else if (idx < 208896)  { o = idx - 204800; KS = 2; ph = g2h; pl = g2l; mtype = 5; }
    else return;
    int t = o & 7;
    int l = (o >> 3) & 63;
    int frag = o >> 9;
    int ks = frag % KS;
    int nfr = frag / KS;
    int n = nfr * 16 + (l & 15);
    int k = ks * 32 + (l >> 4) * 8 + t;
    float v;
    switch (mtype) {
        case 0: v = (n < 256) ? mw1[k * 256 + n] : mw1[(128 + k) * 256 + (n - 256)]; break;
        case 1: v = mw2[k * 128 + n]; break;
        case 2: v = uw1[k * 256 + n]; break;
        case 3: v = uw2[k * 128 + n]; break;
        case 4: v = f1w[k * 64 + n]; break;
        default: v = f2w[k * 64 + n]; break;
    }
    unsigned short hi, lo;
    split_bf(v, hi, lo);
    ph[o] = hi;
    pl[o] = lo;
}

// =================== megakernel: one block per graph ===================
__global__ __launch_bounds__(512, 2) void k_mega(
    const float* __restrict__ nfeat, const float* __restrict__ efeat,
    const float* __restrict__ mfi,
    const float* __restrict__ enw, const float* __restrict__ enb,
    const float* __restrict__ uvg,
    const unsigned short* __restrict__ w1h, const unsigned short* __restrict__ w1l,
    const unsigned short* __restrict__ w2h, const unsigned short* __restrict__ w2l,
    const unsigned short* __restrict__ u1h, const unsigned short* __restrict__ u1l,
    const unsigned short* __restrict__ u2h, const unsigned short* __restrict__ u2l,
    const unsigned short* __restrict__ g1h, const unsigned short* __restrict__ g1l,
    const unsigned short* __restrict__ g2h, const unsigned short* __restrict__ g2l,
    const float* __restrict__ mb2, const float* __restrict__ ub1,
    const float* __restrict__ ub2, const float* __restrict__ f1b,
    const float* __restrict__ f2b,
    const int* __restrict__ fr, const int* __restrict__ to,
    float* __restrict__ out) {
    __shared__ __align__(16) float hS[60][132];
    __shared__ __align__(16) float H1S[45][516];   // overlay: US[60][260]; tail hid/t
    __shared__ __align__(16) float aggS[45][132];  // overlay: B Z-stage; tail la/red
    __shared__ float uS[256], vS[256];
    __shared__ int cfS[144], ctS[144];
    __shared__ float efS[144], msS[144];
    __shared__ float b2S[128], ub1S[256], ub2S[128], f1bS[64], f2bS[64];

    int g = blockIdx.x;
    int tid = threadIdx.x;
    int wid = tid >> 6, lane = tid & 63;
    int l15 = lane & 15, l4 = lane >> 4;
    int rloc = l4 * 4;

    // ---- preload ----
    if (tid < 256) uS[tid] = uvg[tid];
    else vS[tid - 256] = uvg[tid];
    if (tid < 128) b2S[tid] = mb2[tid];
    if (tid < 256) ub1S[tid] = ub1[tid];
    if (tid < 128) ub2S[tid] = ub2[tid];
    if (tid < 64) { f1bS[tid] = f1b[tid]; f2bS[tid] = f2b[tid]; }
    if (tid < EPG) {
        int fn = fr[g * EPG + tid] - g * NPG;
        int tn = to[g * EPG + tid] - g * NPG;
        cfS[tid] = fn < 15 ? fn : fn - 15;
        ctS[tid] = tn < 15 ? tn : tn - 15;
        efS[tid] = efeat[g * EPG + tid];
        msS[tid] = mfi[g * EPG + tid];
    } else if (tid < 144) {
        cfS[tid] = 0; ctS[tid] = 0; efS[tid] = 0.f; msS[tid] = 0.f;
    }
    for (int i = tid; i < 60 * 128; i += 512) {
        int r = i >> 7, d = i & 127;
        hS[r][d] = nfeat[g * NPG + r] * enw[d] + enb[d];
    }
    __syncthreads();

    float* US = &H1S[0][0];                 // [60][260] during C/D
    char* zb = (char*)&aggS[0][0];          // B-phase Z-frag staging

    for (int iter = 0; iter < NPROP; ++iter) {
        // ======== A: H1S = gather(hS) @ W1^T ; wave w -> n-frags w*4..w*4+3 ========
        {
            f32x4 acc[3][4] = {};
#pragma unroll
            for (int ks = 0; ks < 4; ++ks) {
                int k0 = ks * 32 + l4 * 8;
                bf16x8 ah[3], al[3];
#pragma unroll
                for (int i = 0; i < 3; ++i) {
                    int r = i * 16 + l15;
                    int hr = r < 15 ? r : (r < 45 ? r + 15 : 0);
                    float4 a0 = *(const float4*)&hS[hr][k0];
                    float4 a1 = *(const float4*)&hS[hr][k0 + 4];
                    splitv(a0, a1, ah[i], al[i]);
                }
#pragma unroll
                for (int j = 0; j < 4; ++j) {
                    int nfr = wid * 4 + j;
                    int off = ((nfr * 4 + ks) * 64 + lane) * 8;
                    U8 th, tl;
                    th.u = *(const uint4*)(w1h + off);
                    tl.u = *(const uint4*)(w1l + off);
#pragma unroll
                    for (int i = 0; i < 3; ++i) { MFMA3(ah[i], al[i], th.v, tl.v, acc[i][j]); }
                }
            }
#pragma unroll
            for (int i = 0; i < 3; ++i)
#pragma unroll
                for (int j = 0; j < 4; ++j) {
                    int col = wid * 64 + j * 16 + l15;
#pragma unroll
                    for (int r = 0; r < 4; ++r) {
                        int m = i * 16 + rloc + r;
                        if (m < 45) H1S[m][col] = acc[i][j][r];
                    }
                }
        }
        __syncthreads();

        // ======== B: Z(144x256)=relu(H1[f]+H1[t]+ef*u+v); agg += Z@W2 ========
        {
            // preload this wave's 8 W2 (hi,lo) frags into registers (static idx)
            bf16x8 WH[8], WL[8];
#pragma unroll
            for (int ks = 0; ks < 8; ++ks) {
                int off = ((wid * 8 + ks) * 64 + lane) * 8;
                U8 th, tl;
                th.u = *(const uint4*)(w2h + off);
                tl.u = *(const uint4*)(w2l + off);
                WH[ks] = th.v; WL[ks] = tl.v;
            }
            f32x4 accB[9] = {};
#pragma unroll
            for (int ks = 0; ks < 8; ++ks) {
                __syncthreads();   // prior reads of stage done
                for (int u = tid; u < 576; u += 512) {
                    int f = u >> 6, l = u & 63;
                    int e = f * 16 + (l & 15);
                    int k0 = ks * 32 + (l >> 4) * 8;
                    int ee = e < EPG ? e : 0;
                    int cf = cfS[ee], ct = ctS[ee];
                    float ev = e < EPG ? efS[ee] : 0.f;
                    float4 x0 = *(const float4*)&H1S[cf][k0];
                    float4 x1 = *(const float4*)&H1S[cf][k0 + 4];
                    float4 y0 = *(const float4*)&H1S[ct][256 + k0];
                    float4 y1 = *(const float4*)&H1S[ct][256 + k0 + 4];
                    x0.x = fmaxf(x0.x + y0.x + ev * uS[k0 + 0] + vS[k0 + 0], 0.f);
                    x0.y = fmaxf(x0.y + y0.y + ev * uS[k0 + 1] + vS[k0 + 1], 0.f);
                    x0.z = fmaxf(x0.z + y0.z + ev * uS[k0 + 2] + vS[k0 + 2], 0.f);
                    x0.w = fmaxf(x0.w + y0.w + ev * uS[k0 + 3] + vS[k0 + 3], 0.f);
                    x1.x = fmaxf(x1.x + y1.x + ev * uS[k0 + 4] + vS[k0 + 4], 0.f);
                    x1.y = fmaxf(x1.y + y1.y + ev * uS[k0 + 5] + vS[k0 + 5], 0.f);
                    x1.z = fmaxf(x1.z + y1.z + ev * uS[k0 + 6] + vS[k0 + 6], 0.f);
                    x1.w = fmaxf(x1.w + y1.w + ev * uS[k0 + 7] + vS[k0 + 7], 0.f);
                    bf16x8 zh, zl;
                    splitv(x0, x1, zh, zl);
                    U8 sh, sl; sh.v = zh; sl.v = zl;
                    *(uint4*)(zb + f * 2048 + l * 16) = sh.u;
                    *(uint4*)(zb + f * 2048 + 1024 + l * 16) = sl.u;
                }
                __syncthreads();
#pragma unroll
                for (int f = 0; f < 9; ++f) {
                    bf16x8 zh = *(bf16x8*)(zb + f * 2048 + lane * 16);
                    bf16x8 zl = *(bf16x8*)(zb + f * 2048 + 1024 + lane * 16);
                    MFMA3(zh, zl, WH[ks], WL[ks], accB[f]);
                }
            }
            __syncthreads();
            for (int i = tid; i < 45 * 132; i += 512) (&aggS[0][0])[i] = 0.f;
            __syncthreads();
            {
                int col = wid * 16 + l15;
                float bias = b2S[col];
#pragma unroll
                for (int f = 0; f < 9; ++f)
#pragma unroll
                    for (int r = 0; r < 4; ++r) {
                        int e = f * 16 + rloc + r;
                        if (e < EPG)
                            atomicAdd(&aggS[ctS[e]][col], (accB[f][r] + bias) * msS[e]);
                    }
            }
        }
        __syncthreads();

        // ======== C: US[60][256] = relu([agg|h] @ Uw1^T + b1) ; wave w -> nf {2w,2w+1} ========
        {
            // preload 16 (hi,lo) frags (2 nfr x 8 ks) into registers
            bf16x8 CH[2][8], CL[2][8];
#pragma unroll
            for (int j = 0; j < 2; ++j)
#pragma unroll
                for (int ks = 0; ks < 8; ++ks) {
                    int nfr = wid * 2 + j;
                    int off = ((nfr * 8 + ks) * 64 + lane) * 8;
                    U8 th, tl;
                    th.u = *(const uint4*)(u1h + off);
                    tl.u = *(const uint4*)(u1l + off);
                    CH[j][ks] = th.v; CL[j][ks] = tl.v;
                }
            f32x4 accC[4][2] = {};
#pragma unroll
            for (int ks = 0; ks < 8; ++ks) {
                int k0 = ks * 32 + l4 * 8;
#pragma unroll
                for (int mf = 0; mf < 4; ++mf) {
                    int p = mf * 16 + l15;
                    float4 z0, z1;
                    if (ks < 4) {
                        int ar = p < 15 ? p : (p < 60 ? p - 15 : 0);
                        z0 = *(const float4*)&aggS[ar][k0];
                        z1 = *(const float4*)&aggS[ar][k0 + 4];
                        float msk = (p >= 15 && p < 30) ? 0.f : 1.f;
                        z0.x *= msk; z0.y *= msk; z0.z *= msk; z0.w *= msk;
                        z1.x *= msk; z1.y *= msk; z1.z *= msk; z1.w *= msk;
                    } else {
                        int hr = p < 60 ? p : 0;
                        z0 = *(const float4*)&hS[hr][k0 - 128];
                        z1 = *(const float4*)&hS[hr][k0 - 128 + 4];
                    }
                    bf16x8 ah, al;
                    splitv(z0, z1, ah, al);
#pragma unroll
                    for (int j = 0; j < 2; ++j) { MFMA3(ah, al, CH[j][ks], CL[j][ks], accC[mf][j]); }
                }
            }
            __syncthreads();
#pragma unroll
            for (int mf = 0; mf < 4; ++mf)
#pragma unroll
                for (int j = 0; j < 2; ++j) {
                    int col = (wid * 2 + j) * 16 + l15;
                    float bias = ub1S[col];
#pragma unroll
                    for (int r = 0; r < 4; ++r) {
                        int m = mf * 16 + rloc + r;
                        if (m < 60) US[m * 260 + col] = fmaxf(accC[mf][j][r] + bias, 0.f);
                    }
                }
        }
        __syncthreads();

        // ======== D: hS += US @ Uw2^T + b2 ; wave w -> nf w ========
        {
            bf16x8 DH[8], DL[8];
#pragma unroll
            for (int ks = 0; ks < 8; ++ks) {
                int off = ((wid * 8 + ks) * 64 + lane) * 8;
                U8 th, tl;
                th.u = *(const uint4*)(u2h + off);
                tl.u = *(const uint4*)(u2l + off);
                DH[ks] = th.v; DL[ks] = tl.v;
            }
            f32x4 accD[4] = {};
#pragma unroll
            for (int ks = 0; ks < 8; ++ks) {
                int k0 = ks * 32 + l4 * 8;
#pragma unroll
                for (int mf = 0; mf < 4; ++mf) {
                    int p = mf * 16 + l15;
                    int pr = p < 60 ? p : 0;
                    float4 z0 = *(const float4*)&US[pr * 260 + k0];
                    float4 z1 = *(const float4*)&US[pr * 260 + k0 + 4];
                    bf16x8 ah, al;
                    splitv(z0, z1, ah, al);
                    MFMA3(ah, al, DH[ks], DL[ks], accD[mf]);
                }
            }
#pragma unroll
            for (int mf = 0; mf < 4; ++mf) {
                int col = wid * 16 + l15;
                float bias = ub2S[col];
#pragma unroll
                for (int r = 0; r < 4; ++r) {
                    int m = mf * 16 + rloc + r;
                    if (m < 60) hS[m][col] += accD[mf][r] + bias;
                }
            }
        }
        __syncthreads();
    }

    // =================== tail: transform + Sinkhorn + score ===================
    float* hid = &H1S[0][0];        // [45][68]
    float* tS = hid + 45 * 68;      // [45][68]
    float* la = &aggS[0][0];        // [30][33]
    float* red = la + 1024;         // [512]

    if (wid < 6) {  // ft1
        int mf = wid >> 1, nh = wid & 1;
        f32x4 acc[2] = {};
#pragma unroll
        for (int ks = 0; ks < 4; ++ks) {
            int k0 = ks * 32 + l4 * 8;
            int r = mf * 16 + l15;
            int hr = r < 15 ? r : (r < 45 ? r + 15 : 0);
            float4 a0 = *(const float4*)&hS[hr][k0];
            float4 a1 = *(const float4*)&hS[hr][k0 + 4];
            bf16x8 ah, al;
            splitv(a0, a1, ah, al);
#pragma unroll
            for (int j = 0; j < 2; ++j) {
                int nfr = nh * 2 + j;
                int off = ((nfr * 4 + ks) * 64 + lane) * 8;
                U8 th, tl;
                th.u = *(const uint4*)(g1h + off);
                tl.u = *(const uint4*)(g1l + off);
                MFMA3(ah, al, th.v, tl.v, acc[j]);
            }
        }
#pragma unroll
        for (int j = 0; j < 2; ++j) {
            int col = nh * 32 + j * 16 + l15;
            float bias = f1bS[col];
#pragma unroll
            for (int r = 0; r < 4; ++r) {
                int m = mf * 16 + rloc + r;
                if (m < 45) hid[m * 68 + col] = fmaxf(acc[j][r] + bias, 0.f);
            }
        }
    }
    __syncthreads();
    if (wid < 6) {  // ft2
        int mf = wid >> 1, nh = wid & 1;
        f32x4 acc[2] = {};
#pragma unroll
        for (int ks = 0; ks < 2; ++ks) {
            int k0 = ks * 32 + l4 * 8;
            int r = mf * 16 + l15;
            int hr = r < 45 ? r : 0;
            float4 a0 = *(const float4*)&hid[hr * 68 + k0];
            float4 a1 = *(const float4*)&hid[hr * 68 + k0 + 4];
            bf16x8 ah, al;
            splitv(a0, a1, ah, al);
#pragma unroll
            for (int j = 0; j < 2; ++j) {
                int nfr = nh * 2 + j;
                int off = ((nfr * 2 + ks) * 64 + lane) * 8;
                U8 th, tl;
                th.u = *(const uint4*)(g2h + off);
                tl.u = *(const uint4*)(g2l + off);
                MFMA3(ah, al, th.v, tl.v, acc[j]);
            }
        }
#pragma unroll
        for (int j = 0; j < 2; ++j) {
            int col = nh * 32 + j * 16 + l15;
            float bias = f2bS[col];
#pragma unroll
            for (int r = 0; r < 4; ++r) {
                int m = mf * 16 + rloc + r;
                if (m < 45) tS[m * 68 + col] = acc[j][r] + bias;
            }
        }
    }
    __syncthreads();
    for (int e = tid; e < NCC * NCC; e += 512) {
        int q = e / NCC, c = e % NCC;
        float s = 0.f;
        if (q < NQQ) {
#pragma unroll 4
            for (int k = 0; k < TT; k++) s += tS[q * 68 + k] * tS[(15 + c) * 68 + k];
            s *= 10.0f;
        }
        la[q * 33 + c] = s;
    }
    __syncthreads();
    int grp = tid >> 3, k8 = tid & 7;
    for (int it = 0; it < SKI; ++it) {
        if (grp < NCC) {
            float v0, v1, v2, v3, m;
            int c0 = k8 * 4;
            v0 = (c0 + 0 < NCC) ? la[grp * 33 + c0 + 0] : -INFINITY;
            v1 = (c0 + 1 < NCC) ? la[grp * 33 + c0 + 1] : -INFINITY;
            v2 = (c0 + 2 < NCC) ? la[grp * 33 + c0 + 2] : -INFINITY;
            v3 = (c0 + 3 < NCC) ? la[grp * 33 + c0 + 3] : -INFINITY;
            m = fmaxf(fmaxf(v0, v1), fmaxf(v2, v3));
            m = fmaxf(m, __shfl_xor(m, 1));
            m = fmaxf(m, __shfl_xor(m, 2));
            m = fmaxf(m, __shfl_xor(m, 4));
            float s = 0.f;
            if (c0 + 0 < NCC) s += __expf(v0 - m);
            if (c0 + 1 < NCC) s += __expf(v1 - m);
            if (c0 + 2 < NCC) s += __expf(v2 - m);
            if (c0 + 3 < NCC) s += __expf(v3 - m);
            s += __shfl_xor(s, 1);
            s += __shfl_xor(s, 2);
            s += __shfl_xor(s, 4);
            float lse = m + __logf(s);
            if (c0 + 0 < NCC) la[grp * 33 + c0 + 0] = v0 - lse;
            if (c0 + 1 < NCC) la[grp * 33 + c0 + 1] = v1 - lse;
            if (c0 + 2 < NCC) la[grp * 33 + c0 + 2] = v2 - lse;
            if (c0 + 3 < NCC) la[grp * 33 + c0 + 3] = v3 - lse;
        }
        __syncthreads();
        if (grp < NCC) {
            float v0, v1, v2, v3, m;
            int q0 = k8 * 4;
            v0 = (q0 + 0 < NCC) ? la[(q0 + 0) * 33 + grp] : -INFINITY;
            v1 = (q0 + 1 < NCC) ? la[(q0 + 1) * 33 + grp] : -INFINITY;
            v2 = (q0 + 2 < NCC) ? la[(q0 + 2) * 33 + grp] : -INFINITY;
            v3 = (q0 + 3 < NCC) ? la[(q0 + 3) * 33 + grp] : -INFINITY;
            m = fmaxf(fmaxf(v0, v1), fmaxf(v2, v3));
            m = fmaxf(m, __shfl_xor(m, 1));
            m = fmaxf(m, __shfl_xor(m, 2));
            m = fmaxf(m, __shfl_xor(m, 4));
            float s = 0.f;
            if (q0 + 0 < NCC) s += __expf(v0 - m);
            if (q0 + 1 < NCC) s += __expf(v1 - m);
            if (q0 + 2 < NCC) s += __expf(v2 - m);
            if (q0 + 3 < NCC) s += __expf(v3 - m);
            s += __shfl_xor(s, 1);
            s += __shfl_xor(s, 2);
            s += __shfl_xor(s, 4);
            float lse = m + __logf(s);
            if (q0 + 0 < NCC) la[(q0 + 0) * 33 + grp] = v0 - lse;
            if (q0 + 1 < NCC) la[(q0 + 1) * 33 + grp] = v1 - lse;
            if (q0 + 2 < NCC) la[(q0 + 2) * 33 + grp] = v2 - lse;
            if (q0 + 3 < NCC) la[(q0 + 3) * 33 + grp] = v3 - lse;
        }
        __syncthreads();
    }
    for (int e = tid; e < NCC * NCC; e += 512) {
        int q = e / NCC, c = e % NCC;
        la[q * 33 + c] = __expf(la[q * 33 + c]);
    }
    __syncthreads();
    float part = 0.f;
    for (int idx = tid; idx < NCC * D; idx += 512) {
        int q = idx >> 7, d = idx & 127;
        float mv = 0.f;
#pragma unroll 5
        for (int c = 0; c < NCC; c++) mv += la[q * 33 + c] * hS[30 + c][d];
        part += fmaxf(hS[q][d] - mv, 0.f);
    }
    red[tid] = part;
    __syncthreads();
    for (int s2 = 256; s2 > 0; s2 >>= 1) {
        if (tid < s2) red[tid] += red[tid + s2];
        __syncthreads();
    }
    if (tid == 0) out[g] = -red[0];
}

extern "C" void kernel_launch(void* const* d_in, const int* in_sizes, int n_in,
                              void* d_out, int out_size, void* d_ws, size_t ws_size,
                              hipStream_t stream) {
    const float* nf  = (const float*)d_in[0];
    const float* ef  = (const float*)d_in[1];
    const float* mfi = (const float*)d_in[2];
    const float* enw = (const float*)d_in[3];
    const float* enb = (const float*)d_in[4];
    const float* eew = (const float*)d_in[5];
    const float* eeb = (const float*)d_in[6];
    const float* mw1 = (const float*)d_in[7];
    const float* mb1 = (const float*)d_in[8];
    const float* mw2 = (const float*)d_in[9];
    const float* mb2 = (const float*)d_in[10];
    const float* uw1 = (const float*)d_in[11];
    const float* ub1 = (const float*)d_in[12];
    const float* uw2 = (const float*)d_in[13];
    const float* ub2 = (const float*)d_in[14];
    const float* f1w = (const float*)d_in[15];
    const float* f1b = (const float*)d_in[16];
    const float* f2w = (const float*)d_in[17];
    const float* f2b = (const float*)d_in[18];
    const int* fr = (const int*)d_in[19];
    const int* to = (const int*)d_in[20];
    float* out = (float*)d_out;

    char* base = (char*)d_ws;
    float* uv = (float*)base;
    unsigned short* w = (unsigned short*)(base + 4096);
    unsigned short* w1h = w;            unsigned short* w1l = w1h + 65536;
    unsigned short* w2h = w1l + 65536;  unsigned short* w2l = w2h + 32768;
    unsigned short* u1h = w2l + 32768;  unsigned short* u1l = u1h + 65536;
    unsigned short* u2h = u1l + 65536;  unsigned short* u2l = u2h + 32768;
    unsigned short* g1h = u2l + 32768;  unsigned short* g1l = g1h + 8192;
    unsigned short* g2h = g1l + 8192;   unsigned short* g2l = g2h + 4096;

    k_prep_uv<<<1, 256, 0, stream>>>(eew, eeb, mw1, mb1, uv);
    k_prep_w2<<<408, 512, 0, stream>>>(mw1, mw2, uw1, uw2, f1w, f2w,
                                       w1h, w1l, w2h, w2l, u1h, u1l, u2h, u2l,
                                       g1h, g1l, g2h, g2l);
    k_mega<<<BATCH, 512, 0, stream>>>(nf, ef, mfi, enw, enb, uv,
                                      w1h, w1l, w2h, w2l, u1h, u1l, u2h, u2l,
                                      g1h, g1l, g2h, g2l,
                                      mb2, ub1, ub2, f1b, f2b, fr, to, out);
}